// Round 2
// baseline (1565.488 us; speedup 1.0000x reference)
//
#include <hip/hip_runtime.h>
#include <math.h>

#define N_NODES 50000
#define N_EDGES 800000
#define E_TOT   850000   /* edges + self loops */
#define IN_F    128
#define HEADS   4
#define OUT_F   32
#define HF      128      /* HEADS*OUT_F */
#define NEG_SLOPE 0.2f

/* workspace layout (float offsets) */
#define WS_H      0           /* 50000*128 = 6,400,000  */
#define WS_ASRC   6400000     /* 50000*4   = 200,000    */
#define WS_ADST   6600000     /* 200,000                */
#define WS_WUN    6800000     /* 850000*4  = 3,400,000  */
#define WS_PSUM   10200000    /* 3321*4                 */
#define WS_INV    10260000    /* 4                      */
#define NBLK_EDGE 3321        /* ceil(850000/256)       */

static __device__ __forceinline__ float4 ld4(const float* p) {
    return *reinterpret_cast<const float4*>(p);
}

/* out[n][c] = bias[c]  (atomics accumulate on top) */
__global__ __launch_bounds__(256) void k_init_out(const float* __restrict__ bias,
                                                  float* __restrict__ out) {
    int i = blockIdx.x * 256 + threadIdx.x;           /* float4 index, 1.6M total */
    float4 b = reinterpret_cast<const float4*>(bias)[i & 31];
    reinterpret_cast<float4*>(out)[i] = b;
}

/* h = x @ W^T  (+ fused per-node attention pre-reduction)
   block: 256 threads, 32 nodes.  thread: cg = t&31 -> 4 consecutive outputs
   c0 = cg*4; nr = t>>5 -> nodes nr, nr+8, nr+16, nr+24. */
__global__ __launch_bounds__(256) void k_gemm_attprep(
    const float* __restrict__ x, const float* __restrict__ W,
    const float* __restrict__ att, float* __restrict__ h,
    float* __restrict__ a_src, float* __restrict__ a_dst)
{
    __shared__ float xs[32 * 128];   /* x tile  [node][k]   16 KB */
    __shared__ float wt[32 * 128];   /* W^T     [kk][c]     16 KB (k-chunk) */
    const int t  = threadIdx.x;
    const int n0 = blockIdx.x * 32;

    /* stage x tile, coalesced float4 */
    #pragma unroll
    for (int r = 0; r < 4; ++r) {
        int o = r * 1024 + t * 4;
        float4 v = make_float4(0.f, 0.f, 0.f, 0.f);
        if (n0 * 128 + o < N_NODES * 128) v = ld4(x + n0 * 128 + o);
        *reinterpret_cast<float4*>(xs + o) = v;
    }

    const int cg = t & 31;
    const int nr = t >> 5;
    float4 acc[4];
    #pragma unroll
    for (int ni = 0; ni < 4; ++ni) acc[ni] = make_float4(0.f, 0.f, 0.f, 0.f);

    const float4* xs4 = reinterpret_cast<const float4*>(xs);
    const float4* wt4 = reinterpret_cast<const float4*>(wt);

    for (int kt = 0; kt < 4; ++kt) {
        __syncthreads();                       /* protect wt from previous iter */
        {   /* stage W^T chunk: wt[kk][c] = W[c][kt*32+kk] */
            const int c = t >> 1, half = t & 1;
            #pragma unroll
            for (int i = 0; i < 4; ++i) {
                float4 wv = ld4(W + c * 128 + kt * 32 + half * 16 + i * 4);
                int kk = half * 16 + i * 4;
                wt[(kk + 0) * 128 + c] = wv.x;
                wt[(kk + 1) * 128 + c] = wv.y;
                wt[(kk + 2) * 128 + c] = wv.z;
                wt[(kk + 3) * 128 + c] = wv.w;
            }
        }
        __syncthreads();

        #pragma unroll
        for (int kk4 = 0; kk4 < 8; ++kk4) {
            float xv[4][4];
            #pragma unroll
            for (int ni = 0; ni < 4; ++ni)
                *reinterpret_cast<float4*>(xv[ni]) =
                    xs4[(nr + ni * 8) * 32 + kt * 8 + kk4];
            #pragma unroll
            for (int j = 0; j < 4; ++j) {
                float4 wv = wt4[(kk4 * 4 + j) * 32 + cg];
                #pragma unroll
                for (int ni = 0; ni < 4; ++ni) {
                    acc[ni].x += xv[ni][j] * wv.x;
                    acc[ni].y += xv[ni][j] * wv.y;
                    acc[ni].z += xv[ni][j] * wv.z;
                    acc[ni].w += xv[ni][j] * wv.w;
                }
            }
        }
    }

    /* epilogue: store h + fused a_src/a_dst (8-lane groups share (node,head)) */
    const int head = cg >> 3;
    const int f0   = (cg & 7) * 4;
    float4 as = ld4(att + head * 64 + f0);
    float4 ad = ld4(att + head * 64 + 32 + f0);

    #pragma unroll
    for (int ni = 0; ni < 4; ++ni) {
        int n = n0 + nr + ni * 8;
        if (n < N_NODES) {
            *reinterpret_cast<float4*>(&h[n * 128 + cg * 4]) = acc[ni];
            float lx = acc[ni].x > 0.f ? acc[ni].x : NEG_SLOPE * acc[ni].x;
            float ly = acc[ni].y > 0.f ? acc[ni].y : NEG_SLOPE * acc[ni].y;
            float lz = acc[ni].z > 0.f ? acc[ni].z : NEG_SLOPE * acc[ni].z;
            float lw = acc[ni].w > 0.f ? acc[ni].w : NEG_SLOPE * acc[ni].w;
            float ps = lx * as.x + ly * as.y + lz * as.z + lw * as.w;
            float pd = lx * ad.x + ly * ad.y + lz * ad.z + lw * ad.w;
            ps += __shfl_xor(ps, 1); ps += __shfl_xor(ps, 2); ps += __shfl_xor(ps, 4);
            pd += __shfl_xor(pd, 1); pd += __shfl_xor(pd, 2); pd += __shfl_xor(pd, 4);
            if ((t & 7) == 0) {
                a_src[n * 4 + head] = ps;
                a_dst[n * 4 + head] = pd;
            }
        }
    }
}

/* per-edge: w_un[e][h] = exp(a_src[s][h] + a_dst[d][h]); block partial sums */
__global__ __launch_bounds__(256) void k_edge_scores(
    const int* __restrict__ eidx, const float* __restrict__ a_src,
    const float* __restrict__ a_dst, float* __restrict__ w_un,
    float* __restrict__ psum)
{
    __shared__ float4 red[256];
    const int t = threadIdx.x;
    const int g = blockIdx.x * 256 + t;
    float4 w = make_float4(0.f, 0.f, 0.f, 0.f);
    if (g < E_TOT) {
        int s, d;
        if (g < N_EDGES) { s = eidx[g]; d = eidx[N_EDGES + g]; }
        else             { s = d = g - N_EDGES; }
        float4 vs = ld4(a_src + s * 4);
        float4 vd = ld4(a_dst + d * 4);
        w.x = expf(vs.x + vd.x);
        w.y = expf(vs.y + vd.y);
        w.z = expf(vs.z + vd.z);
        w.w = expf(vs.w + vd.w);
        reinterpret_cast<float4*>(w_un)[g] = w;
    }
    red[t] = w;
    __syncthreads();
    for (int sdt = 128; sdt > 0; sdt >>= 1) {
        if (t < sdt) {
            float4 o = red[t + sdt];
            red[t].x += o.x; red[t].y += o.y; red[t].z += o.z; red[t].w += o.w;
        }
        __syncthreads();
    }
    if (t == 0) reinterpret_cast<float4*>(psum)[blockIdx.x] = red[0];
}

/* reduce block partials -> inv_sum per head */
__global__ __launch_bounds__(256) void k_final_sum(const float* __restrict__ psum,
                                                   float* __restrict__ inv) {
    __shared__ float red[256];
    const int t = threadIdx.x;
    const int hsel = t & 3;
    float acc = 0.f;
    for (int i = t >> 2; i < NBLK_EDGE; i += 64) acc += psum[i * 4 + hsel];
    red[t] = acc;
    __syncthreads();
    for (int sdt = 128; sdt >= 4; sdt >>= 1) {
        if (t < sdt) red[t] += red[t + sdt];
        __syncthreads();
    }
    if (t < 4) inv[t] = 1.0f / red[t];
}

/* scatter: out[dst] += h[src] * w   (32 lanes per edge, float4 per lane) */
__global__ __launch_bounds__(256) void k_scatter(
    const int* __restrict__ eidx, const float* __restrict__ h,
    const float* __restrict__ w_un, const float* __restrict__ inv,
    float* __restrict__ out)
{
    const int t = threadIdx.x;
    const int e = blockIdx.x * 8 + (t >> 5);
    if (e >= E_TOT) return;
    const int lane = t & 31;
    const int head = lane >> 3;
    int s, d;
    if (e < N_EDGES) { s = eidx[e]; d = eidx[N_EDGES + e]; }
    else             { s = d = e - N_EDGES; }
    const float wgt = w_un[e * 4 + head] * inv[head];
    float4 hv = ld4(h + s * 128 + lane * 4);
    float* op = out + d * 128 + lane * 4;
    atomicAdd(op + 0, hv.x * wgt);
    atomicAdd(op + 1, hv.y * wgt);
    atomicAdd(op + 2, hv.z * wgt);
    atomicAdd(op + 3, hv.w * wgt);
}

extern "C" void kernel_launch(void* const* d_in, const int* in_sizes, int n_in,
                              void* d_out, int out_size, void* d_ws, size_t ws_size,
                              hipStream_t stream) {
    const float* x    = (const float*)d_in[0];
    const int*   eidx = (const int*)d_in[1];   /* [2][800000], row0=src row1=dst */
    const float* W    = (const float*)d_in[2];
    const float* att  = (const float*)d_in[3];
    const float* bias = (const float*)d_in[4];
    float* out = (float*)d_out;
    float* ws  = (float*)d_ws;

    float* h      = ws + WS_H;
    float* a_src  = ws + WS_ASRC;
    float* a_dst  = ws + WS_ADST;
    float* w_un   = ws + WS_WUN;
    float* psum   = ws + WS_PSUM;
    float* inv    = ws + WS_INV;

    k_init_out    <<<(N_NODES * HF / 4) / 256, 256, 0, stream>>>(bias, out);
    k_gemm_attprep<<<(N_NODES + 31) / 32,      256, 0, stream>>>(x, W, att, h, a_src, a_dst);
    k_edge_scores <<<NBLK_EDGE,                256, 0, stream>>>(eidx, a_src, a_dst, w_un, psum);
    k_final_sum   <<<1,                        256, 0, stream>>>(psum, inv);
    k_scatter     <<<(E_TOT + 7) / 8,          256, 0, stream>>>(eidx, h, w_un, inv, out);
}

// Round 3
// 394.611 us; speedup vs baseline: 3.9672x; 3.9672x over previous
//
#include <hip/hip_runtime.h>
#include <math.h>

#define N_NODES 50000
#define N_EDGES 800000
#define E_TOT   850000   /* edges + self loops */
#define IN_F    128
#define HEADS   4
#define OUT_F   32
#define HF      128      /* HEADS*OUT_F */
#define NEG_SLOPE 0.2f

/* workspace layout (float offsets; int arrays cast in place) */
#define WS_H      0           /* 50000*128 = 6,400,000 floats */
#define WS_ASRC   6400000     /* 200,000 floats */
#define WS_ADST   6600000     /* 200,000 floats */
#define WS_PSUM   6800000     /* NBLK_EDGE*4 floats */
#define WS_INV    6820000     /* 4 floats */
#define WS_CNT    6830000     /* int[50000]  */
#define WS_OFF    6880000     /* int[50001]  */
#define WS_CUR    6932000     /* int[50000]  */
#define WS_CSR    6984000     /* int[800000] */
#define NBLK_EDGE 3321        /* ceil(850000/256) */

static __device__ __forceinline__ float4 ld4(const float* p) {
    return *reinterpret_cast<const float4*>(p);
}

__global__ __launch_bounds__(256) void k_zero_cnt(int* __restrict__ cnt) {
    int i = blockIdx.x * 256 + threadIdx.x;
    if (i < N_NODES) cnt[i] = 0;
}

/* h = x @ W^T  (+ fused per-node attention pre-reduction)
   block: 256 threads, 32 nodes.  thread: cg = t&31 -> 4 consecutive outputs;
   nr = t>>5 -> nodes nr, nr+8, nr+16, nr+24. */
__global__ __launch_bounds__(256) void k_gemm_attprep(
    const float* __restrict__ x, const float* __restrict__ W,
    const float* __restrict__ att, float* __restrict__ h,
    float* __restrict__ a_src, float* __restrict__ a_dst)
{
    __shared__ float xs[32 * 128];
    __shared__ float wt[32 * 128];
    const int t  = threadIdx.x;
    const int n0 = blockIdx.x * 32;

    #pragma unroll
    for (int r = 0; r < 4; ++r) {
        int o = r * 1024 + t * 4;
        float4 v = make_float4(0.f, 0.f, 0.f, 0.f);
        if (n0 * 128 + o < N_NODES * 128) v = ld4(x + n0 * 128 + o);
        *reinterpret_cast<float4*>(xs + o) = v;
    }

    const int cg = t & 31;
    const int nr = t >> 5;
    float4 acc[4];
    #pragma unroll
    for (int ni = 0; ni < 4; ++ni) acc[ni] = make_float4(0.f, 0.f, 0.f, 0.f);

    const float4* xs4 = reinterpret_cast<const float4*>(xs);
    const float4* wt4 = reinterpret_cast<const float4*>(wt);

    for (int kt = 0; kt < 4; ++kt) {
        __syncthreads();
        {   /* stage W^T chunk: wt[kk][c] = W[c][kt*32+kk] */
            const int c = t >> 1, half = t & 1;
            #pragma unroll
            for (int i = 0; i < 4; ++i) {
                float4 wv = ld4(W + c * 128 + kt * 32 + half * 16 + i * 4);
                int kk = half * 16 + i * 4;
                wt[(kk + 0) * 128 + c] = wv.x;
                wt[(kk + 1) * 128 + c] = wv.y;
                wt[(kk + 2) * 128 + c] = wv.z;
                wt[(kk + 3) * 128 + c] = wv.w;
            }
        }
        __syncthreads();

        #pragma unroll
        for (int kk4 = 0; kk4 < 8; ++kk4) {
            float xv[4][4];
            #pragma unroll
            for (int ni = 0; ni < 4; ++ni)
                *reinterpret_cast<float4*>(xv[ni]) =
                    xs4[(nr + ni * 8) * 32 + kt * 8 + kk4];
            #pragma unroll
            for (int j = 0; j < 4; ++j) {
                float4 wv = wt4[(kk4 * 4 + j) * 32 + cg];
                #pragma unroll
                for (int ni = 0; ni < 4; ++ni) {
                    acc[ni].x += xv[ni][j] * wv.x;
                    acc[ni].y += xv[ni][j] * wv.y;
                    acc[ni].z += xv[ni][j] * wv.z;
                    acc[ni].w += xv[ni][j] * wv.w;
                }
            }
        }
    }

    const int head = cg >> 3;
    const int f0   = (cg & 7) * 4;
    float4 as = ld4(att + head * 64 + f0);
    float4 ad = ld4(att + head * 64 + 32 + f0);

    #pragma unroll
    for (int ni = 0; ni < 4; ++ni) {
        int n = n0 + nr + ni * 8;
        if (n < N_NODES) {
            *reinterpret_cast<float4*>(&h[n * 128 + cg * 4]) = acc[ni];
            float lx = acc[ni].x > 0.f ? acc[ni].x : NEG_SLOPE * acc[ni].x;
            float ly = acc[ni].y > 0.f ? acc[ni].y : NEG_SLOPE * acc[ni].y;
            float lz = acc[ni].z > 0.f ? acc[ni].z : NEG_SLOPE * acc[ni].z;
            float lw = acc[ni].w > 0.f ? acc[ni].w : NEG_SLOPE * acc[ni].w;
            float ps = lx * as.x + ly * as.y + lz * as.z + lw * as.w;
            float pd = lx * ad.x + ly * ad.y + lz * ad.z + lw * ad.w;
            ps += __shfl_xor(ps, 1); ps += __shfl_xor(ps, 2); ps += __shfl_xor(ps, 4);
            pd += __shfl_xor(pd, 1); pd += __shfl_xor(pd, 2); pd += __shfl_xor(pd, 4);
            if ((t & 7) == 0) {
                a_src[n * 4 + head] = ps;
                a_dst[n * 4 + head] = pd;
            }
        }
    }
}

/* per-edge: accumulate softmax denominator partials + in-degree counts.
   (no per-edge weight store — weights are recomputed in the gather) */
__global__ __launch_bounds__(256) void k_edge_scores(
    const int* __restrict__ eidx, const float* __restrict__ a_src,
    const float* __restrict__ a_dst, int* __restrict__ cnt,
    float* __restrict__ psum)
{
    __shared__ float4 red[256];
    const int t = threadIdx.x;
    const int g = blockIdx.x * 256 + t;
    float4 w = make_float4(0.f, 0.f, 0.f, 0.f);
    if (g < E_TOT) {
        int s, d;
        if (g < N_EDGES) {
            s = eidx[g]; d = eidx[N_EDGES + g];
            atomicAdd(&cnt[d], 1);
        } else {
            s = d = g - N_EDGES;          /* self loop: implicit in gather */
        }
        float4 vs = ld4(a_src + s * 4);
        float4 vd = ld4(a_dst + d * 4);
        w.x = expf(vs.x + vd.x);
        w.y = expf(vs.y + vd.y);
        w.z = expf(vs.z + vd.z);
        w.w = expf(vs.w + vd.w);
    }
    red[t] = w;
    __syncthreads();
    for (int sdt = 128; sdt > 0; sdt >>= 1) {
        if (t < sdt) {
            float4 o = red[t + sdt];
            red[t].x += o.x; red[t].y += o.y; red[t].z += o.z; red[t].w += o.w;
        }
        __syncthreads();
    }
    if (t == 0) reinterpret_cast<float4*>(psum)[blockIdx.x] = red[0];
}

/* exclusive scan of cnt[50000] -> off[50001]; cursor = off copy */
__global__ __launch_bounds__(256) void k_scan(const int* __restrict__ cnt,
                                              int* __restrict__ off,
                                              int* __restrict__ cursor) {
    __shared__ int part[256];
    const int t = threadIdx.x;
    const int CH = 196;                 /* 256*196 = 50176 >= 50000 */
    const int b = t * CH;
    const int e = min(b + CH, N_NODES);
    int sum = 0;
    for (int i = b; i < e; ++i) sum += cnt[i];
    part[t] = sum;
    __syncthreads();
    for (int d = 1; d < 256; d <<= 1) {
        int v = (t >= d) ? part[t - d] : 0;
        __syncthreads();
        part[t] += v;
        __syncthreads();
    }
    int run = part[t] - sum;            /* exclusive base */
    for (int i = b; i < e; ++i) {
        off[i] = run; cursor[i] = run;
        run += cnt[i];
    }
    if (t == 255) off[N_NODES] = part[255];
}

/* reduce block partials -> inv_sum per head */
__global__ __launch_bounds__(256) void k_final_sum(const float* __restrict__ psum,
                                                   float* __restrict__ inv) {
    __shared__ float red[256];
    const int t = threadIdx.x;
    const int hsel = t & 3;
    float acc = 0.f;
    for (int i = t >> 2; i < NBLK_EDGE; i += 64) acc += psum[i * 4 + hsel];
    red[t] = acc;
    __syncthreads();
    for (int sdt = 128; sdt >= 4; sdt >>= 1) {
        if (t < sdt) red[t] += red[t + sdt];
        __syncthreads();
    }
    if (t < 4) inv[t] = 1.0f / red[t];
}

/* fill CSR: src list per destination (order within a list is irrelevant) */
__global__ __launch_bounds__(256) void k_fill(const int* __restrict__ eidx,
                                              int* __restrict__ cursor,
                                              int* __restrict__ src_csr) {
    int g = blockIdx.x * 256 + threadIdx.x;
    if (g >= N_EDGES) return;
    int s = eidx[g], d = eidx[N_EDGES + g];
    int pos = atomicAdd(&cursor[d], 1);
    src_csr[pos] = s;
}

/* gather: one 32-lane group per dst node; zero fp atomics.
   out[n] = inv * ( h[n]*exp(a_src[n]+a_dst[n]) + sum_e h[s_e]*exp(a_src[s_e]+a_dst[n]) ) + bias */
__global__ __launch_bounds__(256) void k_gather(
    const int* __restrict__ off, const int* __restrict__ src_csr,
    const float* __restrict__ a_src, const float* __restrict__ a_dst,
    const float* __restrict__ h, const float* __restrict__ inv,
    const float* __restrict__ bias, float* __restrict__ out)
{
    const int t = threadIdx.x;
    const int n = blockIdx.x * 8 + (t >> 5);
    if (n >= N_NODES) return;
    const int lane = t & 31;
    const int head = lane >> 3;

    const float invh = inv[head];
    const float adh  = a_dst[n * 4 + head];

    /* self loop */
    float w = expf(a_src[n * 4 + head] + adh);
    float4 hv = ld4(h + n * 128 + lane * 4);
    float4 acc = make_float4(hv.x * w, hv.y * w, hv.z * w, hv.w * w);

    const int beg = off[n], end = off[n + 1];
    int j = beg;
    for (; j + 1 < end; j += 2) {               /* 2-edge unroll: 2x MLP */
        int s0 = src_csr[j], s1 = src_csr[j + 1];
        float a0 = a_src[s0 * 4 + head];
        float a1 = a_src[s1 * 4 + head];
        float4 h0 = ld4(h + s0 * 128 + lane * 4);
        float4 h1 = ld4(h + s1 * 128 + lane * 4);
        float w0 = expf(a0 + adh);
        float w1 = expf(a1 + adh);
        acc.x += h0.x * w0 + h1.x * w1;
        acc.y += h0.y * w0 + h1.y * w1;
        acc.z += h0.z * w0 + h1.z * w1;
        acc.w += h0.w * w0 + h1.w * w1;
    }
    if (j < end) {
        int s0 = src_csr[j];
        float w0 = expf(a_src[s0 * 4 + head] + adh);
        float4 h0 = ld4(h + s0 * 128 + lane * 4);
        acc.x += h0.x * w0; acc.y += h0.y * w0;
        acc.z += h0.z * w0; acc.w += h0.w * w0;
    }

    float4 b = ld4(bias + lane * 4);
    float4 o = make_float4(acc.x * invh + b.x, acc.y * invh + b.y,
                           acc.z * invh + b.z, acc.w * invh + b.w);
    *reinterpret_cast<float4*>(out + n * 128 + lane * 4) = o;
}

extern "C" void kernel_launch(void* const* d_in, const int* in_sizes, int n_in,
                              void* d_out, int out_size, void* d_ws, size_t ws_size,
                              hipStream_t stream) {
    const float* x    = (const float*)d_in[0];
    const int*   eidx = (const int*)d_in[1];   /* [2][800000], row0=src row1=dst */
    const float* W    = (const float*)d_in[2];
    const float* att  = (const float*)d_in[3];
    const float* bias = (const float*)d_in[4];
    float* out = (float*)d_out;
    float* ws  = (float*)d_ws;

    float* h      = ws + WS_H;
    float* a_src  = ws + WS_ASRC;
    float* a_dst  = ws + WS_ADST;
    float* psum   = ws + WS_PSUM;
    float* inv    = ws + WS_INV;
    int*   cnt    = (int*)(ws + WS_CNT);
    int*   off    = (int*)(ws + WS_OFF);
    int*   cursor = (int*)(ws + WS_CUR);
    int*   src_csr= (int*)(ws + WS_CSR);

    k_zero_cnt    <<<(N_NODES + 255) / 256,    256, 0, stream>>>(cnt);
    k_gemm_attprep<<<(N_NODES + 31) / 32,      256, 0, stream>>>(x, W, att, h, a_src, a_dst);
    k_edge_scores <<<NBLK_EDGE,                256, 0, stream>>>(eidx, a_src, a_dst, cnt, psum);
    k_scan        <<<1,                        256, 0, stream>>>(cnt, off, cursor);
    k_final_sum   <<<1,                        256, 0, stream>>>(psum, inv);
    k_fill        <<<(N_EDGES + 255) / 256,    256, 0, stream>>>(eidx, cursor, src_csr);
    k_gather      <<<(N_NODES + 7) / 8,        256, 0, stream>>>(off, src_csr, a_src, a_dst, h, inv, bias, out);
}

// Round 4
// 287.086 us; speedup vs baseline: 5.4530x; 1.3745x over previous
//
#include <hip/hip_runtime.h>
#include <math.h>

#define N_NODES 50000
#define N_EDGES 800000
#define E_TOT   850000   /* edges + self loops */
#define IN_F    128
#define HEADS   4
#define OUT_F   32
#define HF      128      /* HEADS*OUT_F */
#define NEG_SLOPE 0.2f

/* workspace layout (float offsets; int arrays cast in place) */
#define WS_H      0           /* 50000*128 = 6,400,000 floats */
#define WS_ASRC   6400000     /* 200,000 floats */
#define WS_ADST   6600000     /* 200,000 floats */
#define WS_PSUM   6800000     /* NBLK_EDGE*4 floats */
#define WS_INV    6820000     /* 4 floats */
#define WS_CNT    6830000     /* int[50000]  */
#define WS_OFF    6880000     /* int[50001]  */
#define WS_CUR    6932000     /* int[50000]  */
#define WS_CSR    6984000     /* int[800000] */
#define WS_BSUM   7784000     /* int[256]    */
#define NBLK_EDGE 3321        /* ceil(850000/256) */
#define NBLK_SCAN 196         /* ceil(50000/256)  */

static __device__ __forceinline__ float4 ld4(const float* p) {
    return *reinterpret_cast<const float4*>(p);
}

__global__ __launch_bounds__(256) void k_zero_cnt(int* __restrict__ cnt) {
    int i = blockIdx.x * 256 + threadIdx.x;
    if (i < N_NODES) cnt[i] = 0;
}

/* h = x @ W^T  (+ fused per-node attention pre-reduction)
   block: 256 threads, 32 nodes.  thread: cg = t&31 -> 4 consecutive outputs;
   nr = t>>5 -> nodes nr, nr+8, nr+16, nr+24. */
__global__ __launch_bounds__(256) void k_gemm_attprep(
    const float* __restrict__ x, const float* __restrict__ W,
    const float* __restrict__ att, float* __restrict__ h,
    float* __restrict__ a_src, float* __restrict__ a_dst)
{
    __shared__ float xs[32 * 128];
    __shared__ float wt[32 * 128];
    const int t  = threadIdx.x;
    const int n0 = blockIdx.x * 32;

    #pragma unroll
    for (int r = 0; r < 4; ++r) {
        int o = r * 1024 + t * 4;
        float4 v = make_float4(0.f, 0.f, 0.f, 0.f);
        if (n0 * 128 + o < N_NODES * 128) v = ld4(x + n0 * 128 + o);
        *reinterpret_cast<float4*>(xs + o) = v;
    }

    const int cg = t & 31;
    const int nr = t >> 5;
    float4 acc[4];
    #pragma unroll
    for (int ni = 0; ni < 4; ++ni) acc[ni] = make_float4(0.f, 0.f, 0.f, 0.f);

    const float4* xs4 = reinterpret_cast<const float4*>(xs);
    const float4* wt4 = reinterpret_cast<const float4*>(wt);

    for (int kt = 0; kt < 4; ++kt) {
        __syncthreads();
        {   /* stage W^T chunk: wt[kk][c] = W[c][kt*32+kk] */
            const int c = t >> 1, half = t & 1;
            #pragma unroll
            for (int i = 0; i < 4; ++i) {
                float4 wv = ld4(W + c * 128 + kt * 32 + half * 16 + i * 4);
                int kk = half * 16 + i * 4;
                wt[(kk + 0) * 128 + c] = wv.x;
                wt[(kk + 1) * 128 + c] = wv.y;
                wt[(kk + 2) * 128 + c] = wv.z;
                wt[(kk + 3) * 128 + c] = wv.w;
            }
        }
        __syncthreads();

        #pragma unroll
        for (int kk4 = 0; kk4 < 8; ++kk4) {
            float xv[4][4];
            #pragma unroll
            for (int ni = 0; ni < 4; ++ni)
                *reinterpret_cast<float4*>(xv[ni]) =
                    xs4[(nr + ni * 8) * 32 + kt * 8 + kk4];
            #pragma unroll
            for (int j = 0; j < 4; ++j) {
                float4 wv = wt4[(kk4 * 4 + j) * 32 + cg];
                #pragma unroll
                for (int ni = 0; ni < 4; ++ni) {
                    acc[ni].x += xv[ni][j] * wv.x;
                    acc[ni].y += xv[ni][j] * wv.y;
                    acc[ni].z += xv[ni][j] * wv.z;
                    acc[ni].w += xv[ni][j] * wv.w;
                }
            }
        }
    }

    const int head = cg >> 3;
    const int f0   = (cg & 7) * 4;
    float4 as = ld4(att + head * 64 + f0);
    float4 ad = ld4(att + head * 64 + 32 + f0);

    #pragma unroll
    for (int ni = 0; ni < 4; ++ni) {
        int n = n0 + nr + ni * 8;
        if (n < N_NODES) {
            *reinterpret_cast<float4*>(&h[n * 128 + cg * 4]) = acc[ni];
            float lx = acc[ni].x > 0.f ? acc[ni].x : NEG_SLOPE * acc[ni].x;
            float ly = acc[ni].y > 0.f ? acc[ni].y : NEG_SLOPE * acc[ni].y;
            float lz = acc[ni].z > 0.f ? acc[ni].z : NEG_SLOPE * acc[ni].z;
            float lw = acc[ni].w > 0.f ? acc[ni].w : NEG_SLOPE * acc[ni].w;
            float ps = lx * as.x + ly * as.y + lz * as.z + lw * as.w;
            float pd = lx * ad.x + ly * ad.y + lz * ad.z + lw * ad.w;
            ps += __shfl_xor(ps, 1); ps += __shfl_xor(ps, 2); ps += __shfl_xor(ps, 4);
            pd += __shfl_xor(pd, 1); pd += __shfl_xor(pd, 2); pd += __shfl_xor(pd, 4);
            if ((t & 7) == 0) {
                a_src[n * 4 + head] = ps;
                a_dst[n * 4 + head] = pd;
            }
        }
    }
}

/* per-edge: accumulate softmax denominator partials + in-degree counts. */
__global__ __launch_bounds__(256) void k_edge_scores(
    const int* __restrict__ eidx, const float* __restrict__ a_src,
    const float* __restrict__ a_dst, int* __restrict__ cnt,
    float* __restrict__ psum)
{
    __shared__ float4 red[256];
    const int t = threadIdx.x;
    const int g = blockIdx.x * 256 + t;
    float4 w = make_float4(0.f, 0.f, 0.f, 0.f);
    if (g < E_TOT) {
        int s, d;
        if (g < N_EDGES) {
            s = eidx[g]; d = eidx[N_EDGES + g];
            atomicAdd(&cnt[d], 1);
        } else {
            s = d = g - N_EDGES;          /* self loop: implicit in gather */
        }
        float4 vs = ld4(a_src + s * 4);
        float4 vd = ld4(a_dst + d * 4);
        w.x = expf(vs.x + vd.x);
        w.y = expf(vs.y + vd.y);
        w.z = expf(vs.z + vd.z);
        w.w = expf(vs.w + vd.w);
    }
    red[t] = w;
    __syncthreads();
    for (int sdt = 128; sdt > 0; sdt >>= 1) {
        if (t < sdt) {
            float4 o = red[t + sdt];
            red[t].x += o.x; red[t].y += o.y; red[t].z += o.z; red[t].w += o.w;
        }
        __syncthreads();
    }
    if (t == 0) reinterpret_cast<float4*>(psum)[blockIdx.x] = red[0];
}

/* hierarchical exclusive scan, pass 1: per-256-chunk LDS scan */
__global__ __launch_bounds__(256) void k_scan_local(const int* __restrict__ cnt,
                                                    int* __restrict__ off,
                                                    int* __restrict__ bsum) {
    __shared__ int buf[256];
    const int t = threadIdx.x;
    const int i = blockIdx.x * 256 + t;
    int v = (i < N_NODES) ? cnt[i] : 0;
    buf[t] = v;
    __syncthreads();
    for (int d = 1; d < 256; d <<= 1) {
        int u = (t >= d) ? buf[t - d] : 0;
        __syncthreads();
        buf[t] += u;
        __syncthreads();
    }
    if (i < N_NODES) off[i] = buf[t] - v;   /* local exclusive */
    if (t == 255) bsum[blockIdx.x] = buf[255];
}

/* pass 2: scan the 196 chunk sums (single tiny block) */
__global__ __launch_bounds__(256) void k_scan_base(int* __restrict__ bsum,
                                                   int* __restrict__ off) {
    __shared__ int buf[256];
    const int t = threadIdx.x;
    int v = (t < NBLK_SCAN) ? bsum[t] : 0;
    buf[t] = v;
    __syncthreads();
    for (int d = 1; d < 256; d <<= 1) {
        int u = (t >= d) ? buf[t - d] : 0;
        __syncthreads();
        buf[t] += u;
        __syncthreads();
    }
    if (t < NBLK_SCAN) bsum[t] = buf[t] - v;  /* exclusive block base */
    if (t == 255) off[N_NODES] = buf[255];    /* = N_EDGES */
}

/* pass 3: add block base; materialize off + cursor */
__global__ __launch_bounds__(256) void k_scan_add(int* __restrict__ off,
                                                  int* __restrict__ cursor,
                                                  const int* __restrict__ bsum) {
    const int i = blockIdx.x * 256 + threadIdx.x;
    if (i < N_NODES) {
        int v = off[i] + bsum[blockIdx.x];
        off[i] = v;
        cursor[i] = v;
    }
}

/* reduce block partials -> inv_sum per head */
__global__ __launch_bounds__(256) void k_final_sum(const float* __restrict__ psum,
                                                   float* __restrict__ inv) {
    __shared__ float red[256];
    const int t = threadIdx.x;
    const int hsel = t & 3;
    float acc = 0.f;
    for (int i = t >> 2; i < NBLK_EDGE; i += 64) acc += psum[i * 4 + hsel];
    red[t] = acc;
    __syncthreads();
    for (int sdt = 128; sdt >= 4; sdt >>= 1) {
        if (t < sdt) red[t] += red[t + sdt];
        __syncthreads();
    }
    if (t < 4) inv[t] = 1.0f / red[t];
}

/* fill CSR: src list per destination (order within a list is irrelevant) */
__global__ __launch_bounds__(256) void k_fill(const int* __restrict__ eidx,
                                              int* __restrict__ cursor,
                                              int* __restrict__ src_csr) {
    int g = blockIdx.x * 256 + threadIdx.x;
    if (g >= N_EDGES) return;
    int s = eidx[g], d = eidx[N_EDGES + g];
    int pos = atomicAdd(&cursor[d], 1);
    src_csr[pos] = s;
}

/* gather: one 32-lane group per dst node; zero fp atomics; 4-deep unroll. */
__global__ __launch_bounds__(256) void k_gather(
    const int* __restrict__ off, const int* __restrict__ src_csr,
    const float* __restrict__ a_src, const float* __restrict__ a_dst,
    const float* __restrict__ h, const float* __restrict__ inv,
    const float* __restrict__ bias, float* __restrict__ out)
{
    const int t = threadIdx.x;
    const int n = blockIdx.x * 8 + (t >> 5);
    if (n >= N_NODES) return;
    const int lane = t & 31;
    const int head = lane >> 3;

    const float invh = inv[head];
    const float adh  = a_dst[n * 4 + head];

    /* self loop */
    float w = expf(a_src[n * 4 + head] + adh);
    float4 hv = ld4(h + n * 128 + lane * 4);
    float4 acc = make_float4(hv.x * w, hv.y * w, hv.z * w, hv.w * w);

    const int beg = off[n], end = off[n + 1];
    int j = beg;
    for (; j + 3 < end; j += 4) {               /* 4-deep: 4 loads in flight */
        int s0 = src_csr[j],     s1 = src_csr[j + 1];
        int s2 = src_csr[j + 2], s3 = src_csr[j + 3];
        float a0 = a_src[s0 * 4 + head];
        float a1 = a_src[s1 * 4 + head];
        float a2 = a_src[s2 * 4 + head];
        float a3 = a_src[s3 * 4 + head];
        float4 h0 = ld4(h + s0 * 128 + lane * 4);
        float4 h1 = ld4(h + s1 * 128 + lane * 4);
        float4 h2 = ld4(h + s2 * 128 + lane * 4);
        float4 h3 = ld4(h + s3 * 128 + lane * 4);
        float w0 = expf(a0 + adh);
        float w1 = expf(a1 + adh);
        float w2 = expf(a2 + adh);
        float w3 = expf(a3 + adh);
        acc.x += h0.x * w0 + h1.x * w1 + h2.x * w2 + h3.x * w3;
        acc.y += h0.y * w0 + h1.y * w1 + h2.y * w2 + h3.y * w3;
        acc.z += h0.z * w0 + h1.z * w1 + h2.z * w2 + h3.z * w3;
        acc.w += h0.w * w0 + h1.w * w1 + h2.w * w2 + h3.w * w3;
    }
    for (; j < end; ++j) {
        int s0 = src_csr[j];
        float w0 = expf(a_src[s0 * 4 + head] + adh);
        float4 h0 = ld4(h + s0 * 128 + lane * 4);
        acc.x += h0.x * w0; acc.y += h0.y * w0;
        acc.z += h0.z * w0; acc.w += h0.w * w0;
    }

    float4 b = ld4(bias + lane * 4);
    float4 o = make_float4(acc.x * invh + b.x, acc.y * invh + b.y,
                           acc.z * invh + b.z, acc.w * invh + b.w);
    *reinterpret_cast<float4*>(out + n * 128 + lane * 4) = o;
}

extern "C" void kernel_launch(void* const* d_in, const int* in_sizes, int n_in,
                              void* d_out, int out_size, void* d_ws, size_t ws_size,
                              hipStream_t stream) {
    const float* x    = (const float*)d_in[0];
    const int*   eidx = (const int*)d_in[1];   /* [2][800000], row0=src row1=dst */
    const float* W    = (const float*)d_in[2];
    const float* att  = (const float*)d_in[3];
    const float* bias = (const float*)d_in[4];
    float* out = (float*)d_out;
    float* ws  = (float*)d_ws;

    float* h      = ws + WS_H;
    float* a_src  = ws + WS_ASRC;
    float* a_dst  = ws + WS_ADST;
    float* psum   = ws + WS_PSUM;
    float* inv    = ws + WS_INV;
    int*   cnt    = (int*)(ws + WS_CNT);
    int*   off    = (int*)(ws + WS_OFF);
    int*   cursor = (int*)(ws + WS_CUR);
    int*   src_csr= (int*)(ws + WS_CSR);
    int*   bsum   = (int*)(ws + WS_BSUM);

    k_zero_cnt    <<<(N_NODES + 255) / 256,    256, 0, stream>>>(cnt);
    k_gemm_attprep<<<(N_NODES + 31) / 32,      256, 0, stream>>>(x, W, att, h, a_src, a_dst);
    k_edge_scores <<<NBLK_EDGE,                256, 0, stream>>>(eidx, a_src, a_dst, cnt, psum);
    k_scan_local  <<<NBLK_SCAN,                256, 0, stream>>>(cnt, off, bsum);
    k_scan_base   <<<1,                        256, 0, stream>>>(bsum, off);
    k_scan_add    <<<NBLK_SCAN,                256, 0, stream>>>(off, cursor, bsum);
    k_final_sum   <<<1,                        256, 0, stream>>>(psum, inv);
    k_fill        <<<(N_EDGES + 255) / 256,    256, 0, stream>>>(eidx, cursor, src_csr);
    k_gather      <<<(N_NODES + 7) / 8,        256, 0, stream>>>(off, src_csr, a_src, a_dst, h, inv, bias, out);
}

// Round 6
// 277.121 us; speedup vs baseline: 5.6491x; 1.0360x over previous
//
#include <hip/hip_runtime.h>
#include <math.h>

#define N_NODES 50000
#define N_EDGES 800000
#define E_TOT   850000   /* edges + self loops */
#define IN_F    128
#define HEADS   4
#define OUT_F   32
#define HF      128      /* HEADS*OUT_F */
#define NEG_SLOPE 0.2f

/* workspace layout (float offsets; int arrays cast in place) */
#define WS_G      0           /* g = h*exp(a_src): 50000*128 floats */
#define WS_ES     6400000     /* exp(a_src): 200,000 floats */
#define WS_ED     6600000     /* exp(a_dst): 200,000 floats */
#define WS_PSUM   6800000     /* NBLK_EDGE*4 floats */
#define WS_INV    6820000     /* 4 floats */
#define WS_CNT    6830000     /* int[50000]  */
#define WS_OFF    6880000     /* int[50001]  */
#define WS_CUR    6932000     /* int[50000]  */
#define WS_CSR    6984000     /* int[800000] */
#define WS_BSUM   7784000     /* int[256]    */
#define NBLK_EDGE 3321        /* ceil(850000/256) */
#define NBLK_SCAN 196         /* ceil(50000/256)  */

static __device__ __forceinline__ float4 ld4(const float* p) {
    return *reinterpret_cast<const float4*>(p);
}

/* GEMM + fused epilogue: g = (x@W^T)*exp(a_src), es/ed tables, zero cnt.
   block: 256 threads, 32 nodes. */
__global__ __launch_bounds__(256) void k_gemm_attprep(
    const float* __restrict__ x, const float* __restrict__ W,
    const float* __restrict__ att, float* __restrict__ g,
    float* __restrict__ es, float* __restrict__ ed,
    int* __restrict__ cnt)
{
    __shared__ float xs[32 * 128];
    __shared__ float wt[32 * 128];
    const int t  = threadIdx.x;
    const int n0 = blockIdx.x * 32;

    /* fold in: zero the in-degree counters (consumed by the NEXT kernel) */
    if (t < 32) {
        int z = blockIdx.x * 32 + t;
        if (z < N_NODES) cnt[z] = 0;
    }

    #pragma unroll
    for (int r = 0; r < 4; ++r) {
        int o = r * 1024 + t * 4;
        float4 v = make_float4(0.f, 0.f, 0.f, 0.f);
        if (n0 * 128 + o < N_NODES * 128) v = ld4(x + n0 * 128 + o);
        *reinterpret_cast<float4*>(xs + o) = v;
    }

    const int cg = t & 31;
    const int nr = t >> 5;
    float4 acc[4];
    #pragma unroll
    for (int ni = 0; ni < 4; ++ni) acc[ni] = make_float4(0.f, 0.f, 0.f, 0.f);

    const float4* xs4 = reinterpret_cast<const float4*>(xs);
    const float4* wt4 = reinterpret_cast<const float4*>(wt);

    for (int kt = 0; kt < 4; ++kt) {
        __syncthreads();
        {   /* stage W^T chunk: wt[kk][c] = W[c][kt*32+kk] */
            const int c = t >> 1, half = t & 1;
            #pragma unroll
            for (int i = 0; i < 4; ++i) {
                float4 wv = ld4(W + c * 128 + kt * 32 + half * 16 + i * 4);
                int kk = half * 16 + i * 4;
                wt[(kk + 0) * 128 + c] = wv.x;
                wt[(kk + 1) * 128 + c] = wv.y;
                wt[(kk + 2) * 128 + c] = wv.z;
                wt[(kk + 3) * 128 + c] = wv.w;
            }
        }
        __syncthreads();

        #pragma unroll
        for (int kk4 = 0; kk4 < 8; ++kk4) {
            float xv[4][4];
            #pragma unroll
            for (int ni = 0; ni < 4; ++ni)
                *reinterpret_cast<float4*>(xv[ni]) =
                    xs4[(nr + ni * 8) * 32 + kt * 8 + kk4];
            #pragma unroll
            for (int j = 0; j < 4; ++j) {
                float4 wv = wt4[(kk4 * 4 + j) * 32 + cg];
                #pragma unroll
                for (int ni = 0; ni < 4; ++ni) {
                    acc[ni].x += xv[ni][j] * wv.x;
                    acc[ni].y += xv[ni][j] * wv.y;
                    acc[ni].z += xv[ni][j] * wv.z;
                    acc[ni].w += xv[ni][j] * wv.w;
                }
            }
        }
    }

    const int head = cg >> 3;
    const int f0   = (cg & 7) * 4;
    float4 as = ld4(att + head * 64 + f0);
    float4 ad = ld4(att + head * 64 + 32 + f0);

    #pragma unroll
    for (int ni = 0; ni < 4; ++ni) {
        int n = n0 + nr + ni * 8;
        if (n < N_NODES) {
            float lx = acc[ni].x > 0.f ? acc[ni].x : NEG_SLOPE * acc[ni].x;
            float ly = acc[ni].y > 0.f ? acc[ni].y : NEG_SLOPE * acc[ni].y;
            float lz = acc[ni].z > 0.f ? acc[ni].z : NEG_SLOPE * acc[ni].z;
            float lw = acc[ni].w > 0.f ? acc[ni].w : NEG_SLOPE * acc[ni].w;
            float ps = lx * as.x + ly * as.y + lz * as.z + lw * as.w;
            float pd = lx * ad.x + ly * ad.y + lz * ad.z + lw * ad.w;
            ps += __shfl_xor(ps, 1); ps += __shfl_xor(ps, 2); ps += __shfl_xor(ps, 4);
            pd += __shfl_xor(pd, 1); pd += __shfl_xor(pd, 2); pd += __shfl_xor(pd, 4);
            float esv = expf(ps);                      /* all 8 lanes agree */
            float4 gv = make_float4(acc[ni].x * esv, acc[ni].y * esv,
                                    acc[ni].z * esv, acc[ni].w * esv);
            *reinterpret_cast<float4*>(&g[n * 128 + cg * 4]) = gv;
            if ((t & 7) == 0) {
                es[n * 4 + head] = esv;
                ed[n * 4 + head] = expf(pd);
            }
        }
    }
}

/* per-edge: denominator partials w = es[s]*ed[d] (no expf) + in-degree count */
__global__ __launch_bounds__(256) void k_edge_scores(
    const int* __restrict__ eidx, const float* __restrict__ es,
    const float* __restrict__ ed, int* __restrict__ cnt,
    float* __restrict__ psum)
{
    __shared__ float4 red[256];
    const int t = threadIdx.x;
    const int g = blockIdx.x * 256 + t;
    float4 w = make_float4(0.f, 0.f, 0.f, 0.f);
    if (g < E_TOT) {
        int s, d;
        if (g < N_EDGES) {
            s = eidx[g]; d = eidx[N_EDGES + g];
            atomicAdd(&cnt[d], 1);
        } else {
            s = d = g - N_EDGES;          /* self loop: implicit in gather */
        }
        float4 vs = ld4(es + s * 4);
        float4 vd = ld4(ed + d * 4);
        w.x = vs.x * vd.x;
        w.y = vs.y * vd.y;
        w.z = vs.z * vd.z;
        w.w = vs.w * vd.w;
    }
    red[t] = w;
    __syncthreads();
    for (int sdt = 128; sdt > 0; sdt >>= 1) {
        if (t < sdt) {
            float4 o = red[t + sdt];
            red[t].x += o.x; red[t].y += o.y; red[t].z += o.z; red[t].w += o.w;
        }
        __syncthreads();
    }
    if (t == 0) reinterpret_cast<float4*>(psum)[blockIdx.x] = red[0];
}

/* hierarchical exclusive scan, pass 1: per-256-chunk LDS scan */
__global__ __launch_bounds__(256) void k_scan_local(const int* __restrict__ cnt,
                                                    int* __restrict__ off,
                                                    int* __restrict__ bsum) {
    __shared__ int buf[256];
    const int t = threadIdx.x;
    const int i = blockIdx.x * 256 + t;
    int v = (i < N_NODES) ? cnt[i] : 0;
    buf[t] = v;
    __syncthreads();
    for (int d = 1; d < 256; d <<= 1) {
        int u = (t >= d) ? buf[t - d] : 0;
        __syncthreads();
        buf[t] += u;
        __syncthreads();
    }
    if (i < N_NODES) off[i] = buf[t] - v;   /* local exclusive */
    if (t == 255) bsum[blockIdx.x] = buf[255];
}

/* fused single-block pass: inv-sum per head + scan of chunk sums */
__global__ __launch_bounds__(256) void k_small(const float* __restrict__ psum,
                                               float* __restrict__ inv,
                                               int* __restrict__ bsum,
                                               int* __restrict__ off) {
    __shared__ float fred[256];
    __shared__ int   ired[256];
    const int t = threadIdx.x;

    /* part 1: softmax denominator -> inv per head */
    const int hsel = t & 3;
    float acc = 0.f;
    for (int i = t >> 2; i < NBLK_EDGE; i += 64) acc += psum[i * 4 + hsel];
    fred[t] = acc;
    __syncthreads();
    for (int sdt = 128; sdt >= 4; sdt >>= 1) {
        if (t < sdt) fred[t] += fred[t + sdt];
        __syncthreads();
    }
    if (t < 4) inv[t] = 1.0f / fred[t];

    /* part 2: exclusive scan of the 196 chunk sums */
    int v = (t < NBLK_SCAN) ? bsum[t] : 0;
    ired[t] = v;
    __syncthreads();
    for (int d = 1; d < 256; d <<= 1) {
        int u = (t >= d) ? ired[t - d] : 0;
        __syncthreads();
        ired[t] += u;
        __syncthreads();
    }
    if (t < NBLK_SCAN) bsum[t] = ired[t] - v;  /* exclusive block base */
    if (t == 255) off[N_NODES] = ired[255];    /* = N_EDGES */
}

/* pass 3: add block base; materialize off + cursor */
__global__ __launch_bounds__(256) void k_scan_add(int* __restrict__ off,
                                                  int* __restrict__ cursor,
                                                  const int* __restrict__ bsum) {
    const int i = blockIdx.x * 256 + threadIdx.x;
    if (i < N_NODES) {
        int v = off[i] + bsum[blockIdx.x];
        off[i] = v;
        cursor[i] = v;
    }
}

/* fill CSR: src list per destination (order within a list is irrelevant) */
__global__ __launch_bounds__(256) void k_fill(const int* __restrict__ eidx,
                                              int* __restrict__ cursor,
                                              int* __restrict__ src_csr) {
    int g = blockIdx.x * 256 + threadIdx.x;
    if (g >= N_EDGES) return;
    int s = eidx[g], d = eidx[N_EDGES + g];
    int pos = atomicAdd(&cursor[d], 1);
    src_csr[pos] = s;
}

/* gather: pure sparse row-sum of g, then one scale by inv*ed[d].
   out[n] = inv * ed[n] * ( g[n] + sum_e g[s_e] ) + bias */
__global__ __launch_bounds__(256) void k_gather(
    const int* __restrict__ off, const int* __restrict__ src_csr,
    const float* __restrict__ ed, const float* __restrict__ g,
    const float* __restrict__ inv, const float* __restrict__ bias,
    float* __restrict__ out)
{
    const int t = threadIdx.x;
    const int n = blockIdx.x * 8 + (t >> 5);
    if (n >= N_NODES) return;
    const int lane = t & 31;
    const int head = lane >> 3;

    /* self loop */
    float4 acc = ld4(g + n * 128 + lane * 4);

    const int beg = off[n], end = off[n + 1];
    int j = beg;
    for (; j + 3 < end; j += 4) {               /* 4 rows in flight */
        int s0 = src_csr[j],     s1 = src_csr[j + 1];
        int s2 = src_csr[j + 2], s3 = src_csr[j + 3];
        float4 g0 = ld4(g + s0 * 128 + lane * 4);
        float4 g1 = ld4(g + s1 * 128 + lane * 4);
        float4 g2 = ld4(g + s2 * 128 + lane * 4);
        float4 g3 = ld4(g + s3 * 128 + lane * 4);
        acc.x += g0.x + g1.x + g2.x + g3.x;
        acc.y += g0.y + g1.y + g2.y + g3.y;
        acc.z += g0.z + g1.z + g2.z + g3.z;
        acc.w += g0.w + g1.w + g2.w + g3.w;
    }
    for (; j < end; ++j) {
        int s0 = src_csr[j];
        float4 g0 = ld4(g + s0 * 128 + lane * 4);
        acc.x += g0.x; acc.y += g0.y; acc.z += g0.z; acc.w += g0.w;
    }

    const float sc = inv[head] * ed[n * 4 + head];
    float4 b = ld4(bias + lane * 4);
    float4 o = make_float4(acc.x * sc + b.x, acc.y * sc + b.y,
                           acc.z * sc + b.z, acc.w * sc + b.w);
    *reinterpret_cast<float4*>(out + n * 128 + lane * 4) = o;
}

extern "C" void kernel_launch(void* const* d_in, const int* in_sizes, int n_in,
                              void* d_out, int out_size, void* d_ws, size_t ws_size,
                              hipStream_t stream) {
    const float* x    = (const float*)d_in[0];
    const int*   eidx = (const int*)d_in[1];   /* [2][800000], row0=src row1=dst */
    const float* W    = (const float*)d_in[2];
    const float* att  = (const float*)d_in[3];
    const float* bias = (const float*)d_in[4];
    float* out = (float*)d_out;
    float* ws  = (float*)d_ws;

    float* g      = ws + WS_G;
    float* es     = ws + WS_ES;
    float* ed     = ws + WS_ED;
    float* psum   = ws + WS_PSUM;
    float* inv    = ws + WS_INV;
    int*   cnt    = (int*)(ws + WS_CNT);
    int*   off    = (int*)(ws + WS_OFF);
    int*   cursor = (int*)(ws + WS_CUR);
    int*   src_csr= (int*)(ws + WS_CSR);
    int*   bsum   = (int*)(ws + WS_BSUM);

    k_gemm_attprep<<<(N_NODES + 31) / 32,      256, 0, stream>>>(x, W, att, g, es, ed, cnt);
    k_edge_scores <<<NBLK_EDGE,                256, 0, stream>>>(eidx, es, ed, cnt, psum);
    k_scan_local  <<<NBLK_SCAN,                256, 0, stream>>>(cnt, off, bsum);
    k_small       <<<1,                        256, 0, stream>>>(psum, inv, bsum, off);
    k_scan_add    <<<NBLK_SCAN,                256, 0, stream>>>(off, cursor, bsum);
    k_fill        <<<(N_EDGES + 255) / 256,    256, 0, stream>>>(eidx, cursor, src_csr);
    k_gather      <<<(N_NODES + 7) / 8,        256, 0, stream>>>(off, src_csr, ed, g, inv, bias, out);
}

// Round 7
// 227.874 us; speedup vs baseline: 6.8700x; 1.2161x over previous
//
#include <hip/hip_runtime.h>
#include <math.h>

#define N_NODES 50000
#define N_EDGES 800000
#define E_TOT   850000   /* edges + self loops */
#define IN_F    128
#define HEADS   4
#define OUT_F   32
#define HF      128      /* HEADS*OUT_F */
#define NEG_SLOPE 0.2f
#define ELLW    40       /* slots per node; P(deg>40 | Poisson 16) ~ 2e-9 */
#define OVF_CAP 4096

/* workspace layout (float offsets; int arrays cast in place) */
#define WS_G      0           /* g = h*exp(a_src): 50000*128 floats */
#define WS_ES     6400000     /* exp(a_src): 200,000 floats */
#define WS_ED     6600000     /* exp(a_dst): 200,000 floats */
#define WS_PSUM   6800000     /* NBLK_EDGE*4 floats */
#define WS_INV    6820000     /* 4 floats */
#define WS_CNT    6830000     /* int[50000]  */
#define WS_ELL    6880000     /* int[50000*40] = 2,000,000 */
#define WS_OVFC   8880000     /* int[1] + pad */
#define WS_OVFS   8880064     /* int[OVF_CAP] */
#define WS_OVFD   8884160     /* int[OVF_CAP] */
#define NBLK_EDGE 3321        /* ceil(850000/256) */

static __device__ __forceinline__ float4 ld4(const float* p) {
    return *reinterpret_cast<const float4*>(p);
}

/* GEMM + fused epilogue: g = (x@W^T)*exp(a_src), es/ed tables, zero cnt/ovf.
   block: 256 threads, 32 nodes. */
__global__ __launch_bounds__(256) void k_gemm_attprep(
    const float* __restrict__ x, const float* __restrict__ W,
    const float* __restrict__ att, float* __restrict__ g,
    float* __restrict__ es, float* __restrict__ ed,
    int* __restrict__ cnt, int* __restrict__ ovf_cnt)
{
    __shared__ float xs[32 * 128];
    __shared__ float wt[32 * 128];
    const int t  = threadIdx.x;
    const int n0 = blockIdx.x * 32;

    /* fold in: zero in-degree counters + overflow counter */
    if (t < 32) {
        int z = n0 + t;
        if (z < N_NODES) cnt[z] = 0;
    }
    if (blockIdx.x == 0 && t == 0) *ovf_cnt = 0;

    #pragma unroll
    for (int r = 0; r < 4; ++r) {
        int o = r * 1024 + t * 4;
        float4 v = make_float4(0.f, 0.f, 0.f, 0.f);
        if (n0 * 128 + o < N_NODES * 128) v = ld4(x + n0 * 128 + o);
        *reinterpret_cast<float4*>(xs + o) = v;
    }

    const int cg = t & 31;
    const int nr = t >> 5;
    float4 acc[4];
    #pragma unroll
    for (int ni = 0; ni < 4; ++ni) acc[ni] = make_float4(0.f, 0.f, 0.f, 0.f);

    const float4* xs4 = reinterpret_cast<const float4*>(xs);
    const float4* wt4 = reinterpret_cast<const float4*>(wt);

    for (int kt = 0; kt < 4; ++kt) {
        __syncthreads();
        {   /* stage W^T chunk: wt[kk][c] = W[c][kt*32+kk] */
            const int c = t >> 1, half = t & 1;
            #pragma unroll
            for (int i = 0; i < 4; ++i) {
                float4 wv = ld4(W + c * 128 + kt * 32 + half * 16 + i * 4);
                int kk = half * 16 + i * 4;
                wt[(kk + 0) * 128 + c] = wv.x;
                wt[(kk + 1) * 128 + c] = wv.y;
                wt[(kk + 2) * 128 + c] = wv.z;
                wt[(kk + 3) * 128 + c] = wv.w;
            }
        }
        __syncthreads();

        #pragma unroll
        for (int kk4 = 0; kk4 < 8; ++kk4) {
            float xv[4][4];
            #pragma unroll
            for (int ni = 0; ni < 4; ++ni)
                *reinterpret_cast<float4*>(xv[ni]) =
                    xs4[(nr + ni * 8) * 32 + kt * 8 + kk4];
            #pragma unroll
            for (int j = 0; j < 4; ++j) {
                float4 wv = wt4[(kk4 * 4 + j) * 32 + cg];
                #pragma unroll
                for (int ni = 0; ni < 4; ++ni) {
                    acc[ni].x += xv[ni][j] * wv.x;
                    acc[ni].y += xv[ni][j] * wv.y;
                    acc[ni].z += xv[ni][j] * wv.z;
                    acc[ni].w += xv[ni][j] * wv.w;
                }
            }
        }
    }

    const int head = cg >> 3;
    const int f0   = (cg & 7) * 4;
    float4 as = ld4(att + head * 64 + f0);
    float4 ad = ld4(att + head * 64 + 32 + f0);

    #pragma unroll
    for (int ni = 0; ni < 4; ++ni) {
        int n = n0 + nr + ni * 8;
        if (n < N_NODES) {
            float lx = acc[ni].x > 0.f ? acc[ni].x : NEG_SLOPE * acc[ni].x;
            float ly = acc[ni].y > 0.f ? acc[ni].y : NEG_SLOPE * acc[ni].y;
            float lz = acc[ni].z > 0.f ? acc[ni].z : NEG_SLOPE * acc[ni].z;
            float lw = acc[ni].w > 0.f ? acc[ni].w : NEG_SLOPE * acc[ni].w;
            float ps = lx * as.x + ly * as.y + lz * as.z + lw * as.w;
            float pd = lx * ad.x + ly * ad.y + lz * ad.z + lw * ad.w;
            ps += __shfl_xor(ps, 1); ps += __shfl_xor(ps, 2); ps += __shfl_xor(ps, 4);
            pd += __shfl_xor(pd, 1); pd += __shfl_xor(pd, 2); pd += __shfl_xor(pd, 4);
            float esv = expf(ps);                      /* all 8 lanes agree */
            float4 gv = make_float4(acc[ni].x * esv, acc[ni].y * esv,
                                    acc[ni].z * esv, acc[ni].w * esv);
            *reinterpret_cast<float4*>(&g[n * 128 + cg * 4]) = gv;
            if ((t & 7) == 0) {
                es[n * 4 + head] = esv;
                ed[n * 4 + head] = expf(pd);
            }
        }
    }
}

/* ONE edge pass: ELL slot assign (count+fill fused) + denominator partials.
   threads [0,800K): real edges; [800K,850K): self-loop denominator terms. */
__global__ __launch_bounds__(256) void k_edge_fill_denom(
    const int* __restrict__ eidx, const float* __restrict__ es,
    const float* __restrict__ ed, int* __restrict__ cnt,
    int* __restrict__ ell, int* __restrict__ ovf_cnt,
    int* __restrict__ ovf_s, int* __restrict__ ovf_d,
    float* __restrict__ psum)
{
    __shared__ float4 red[256];
    const int t = threadIdx.x;
    const int e = blockIdx.x * 256 + t;
    float4 w = make_float4(0.f, 0.f, 0.f, 0.f);
    if (e < E_TOT) {
        int s, d;
        if (e < N_EDGES) {
            s = eidx[e]; d = eidx[N_EDGES + e];
            int pos = atomicAdd(&cnt[d], 1);
            if (pos < ELLW) {
                ell[d * ELLW + pos] = s;
            } else {
                int o = atomicAdd(ovf_cnt, 1);
                if (o < OVF_CAP) { ovf_s[o] = s; ovf_d[o] = d; }
            }
        } else {
            s = d = e - N_EDGES;          /* self loop: denom term only */
        }
        float4 vs = ld4(es + s * 4);
        float4 vd = ld4(ed + d * 4);
        w.x = vs.x * vd.x;
        w.y = vs.y * vd.y;
        w.z = vs.z * vd.z;
        w.w = vs.w * vd.w;
    }
    red[t] = w;
    __syncthreads();
    for (int sdt = 128; sdt > 0; sdt >>= 1) {
        if (t < sdt) {
            float4 o = red[t + sdt];
            red[t].x += o.x; red[t].y += o.y; red[t].z += o.z; red[t].w += o.w;
        }
        __syncthreads();
    }
    if (t == 0) reinterpret_cast<float4*>(psum)[blockIdx.x] = red[0];
}

/* reduce block partials -> inv_sum per head */
__global__ __launch_bounds__(256) void k_inv(const float* __restrict__ psum,
                                             float* __restrict__ inv) {
    __shared__ float red[256];
    const int t = threadIdx.x;
    const int hsel = t & 3;
    float acc = 0.f;
    for (int i = t >> 2; i < NBLK_EDGE; i += 64) acc += psum[i * 4 + hsel];
    red[t] = acc;
    __syncthreads();
    for (int sdt = 128; sdt >= 4; sdt >>= 1) {
        if (t < sdt) red[t] += red[t + sdt];
        __syncthreads();
    }
    if (t < 4) inv[t] = 1.0f / red[t];
}

/* gather (ELL): pure sparse row-sum of g, then one scale by inv*ed[d].
   out[n] = inv * ed[n] * ( g[n] + sum_k g[ell[n][k]] ) + bias */
__global__ __launch_bounds__(256) void k_gather(
    const int* __restrict__ cnt, const int* __restrict__ ell,
    const float* __restrict__ ed, const float* __restrict__ g,
    const float* __restrict__ inv, const float* __restrict__ bias,
    float* __restrict__ out)
{
    const int t = threadIdx.x;
    const int n = blockIdx.x * 8 + (t >> 5);
    if (n >= N_NODES) return;
    const int lane = t & 31;
    const int head = lane >> 3;

    /* self loop */
    float4 acc = ld4(g + n * 128 + lane * 4);

    const int deg = min(cnt[n], ELLW);
    const int* __restrict__ row = ell + n * ELLW;
    int j = 0;
    for (; j + 3 < deg; j += 4) {               /* 4 rows in flight */
        int s0 = row[j],     s1 = row[j + 1];
        int s2 = row[j + 2], s3 = row[j + 3];
        float4 g0 = ld4(g + s0 * 128 + lane * 4);
        float4 g1 = ld4(g + s1 * 128 + lane * 4);
        float4 g2 = ld4(g + s2 * 128 + lane * 4);
        float4 g3 = ld4(g + s3 * 128 + lane * 4);
        acc.x += g0.x + g1.x + g2.x + g3.x;
        acc.y += g0.y + g1.y + g2.y + g3.y;
        acc.z += g0.z + g1.z + g2.z + g3.z;
        acc.w += g0.w + g1.w + g2.w + g3.w;
    }
    for (; j < deg; ++j) {
        int s0 = row[j];
        float4 g0 = ld4(g + s0 * 128 + lane * 4);
        acc.x += g0.x; acc.y += g0.y; acc.z += g0.z; acc.w += g0.w;
    }

    const float sc = inv[head] * ed[n * 4 + head];
    float4 b = ld4(bias + lane * 4);
    float4 o = make_float4(acc.x * sc + b.x, acc.y * sc + b.y,
                           acc.z * sc + b.z, acc.w * sc + b.w);
    *reinterpret_cast<float4*>(out + n * 128 + lane * 4) = o;
}

/* overflow fixup (expected 0 edges): out[d] += inv*ed[d]*g[s] via atomics */
__global__ __launch_bounds__(256) void k_overflow(
    const int* __restrict__ ovf_cnt, const int* __restrict__ ovf_s,
    const int* __restrict__ ovf_d, const float* __restrict__ ed,
    const float* __restrict__ g, const float* __restrict__ inv,
    float* __restrict__ out)
{
    const int m = min(*ovf_cnt, OVF_CAP);
    const int t = threadIdx.x;
    const int lane = t & 31;
    const int head = lane >> 3;
    for (int i = t >> 5; i < m; i += 8) {
        int s = ovf_s[i], d = ovf_d[i];
        float w = inv[head] * ed[d * 4 + head];
        float4 gv = ld4(g + s * 128 + lane * 4);
        float* op = out + d * 128 + lane * 4;
        atomicAdd(op + 0, gv.x * w);
        atomicAdd(op + 1, gv.y * w);
        atomicAdd(op + 2, gv.z * w);
        atomicAdd(op + 3, gv.w * w);
    }
}

extern "C" void kernel_launch(void* const* d_in, const int* in_sizes, int n_in,
                              void* d_out, int out_size, void* d_ws, size_t ws_size,
                              hipStream_t stream) {
    const float* x    = (const float*)d_in[0];
    const int*   eidx = (const int*)d_in[1];   /* [2][800000], row0=src row1=dst */
    const float* W    = (const float*)d_in[2];
    const float* att  = (const float*)d_in[3];
    const float* bias = (const float*)d_in[4];
    float* out = (float*)d_out;
    float* ws  = (float*)d_ws;

    float* g      = ws + WS_G;
    float* es     = ws + WS_ES;
    float* ed     = ws + WS_ED;
    float* psum   = ws + WS_PSUM;
    float* inv    = ws + WS_INV;
    int*   cnt    = (int*)(ws + WS_CNT);
    int*   ell    = (int*)(ws + WS_ELL);
    int*   ovfc   = (int*)(ws + WS_OVFC);
    int*   ovfs   = (int*)(ws + WS_OVFS);
    int*   ovfd   = (int*)(ws + WS_OVFD);

    k_gemm_attprep   <<<(N_NODES + 31) / 32,   256, 0, stream>>>(x, W, att, g, es, ed, cnt, ovfc);
    k_edge_fill_denom<<<NBLK_EDGE,             256, 0, stream>>>(eidx, es, ed, cnt, ell, ovfc, ovfs, ovfd, psum);
    k_inv            <<<1,                     256, 0, stream>>>(psum, inv);
    k_gather         <<<(N_NODES + 7) / 8,     256, 0, stream>>>(cnt, ell, ed, g, inv, bias, out);
    k_overflow       <<<1,                     256, 0, stream>>>(ovfc, ovfs, ovfd, ed, g, inv, out);
}